// Round 14
// baseline (333.595 us; speedup 1.0000x reference)
//
#include <hip/hip_runtime.h>
#include <hip/hip_fp16.h>
#include <math.h>

#define F_IN 128
#define F_HID 64
#define NWG 256      // partition chunks
#define PT 1024      // threads per partition block
#define BSH 7        // dst bucket shift (128 nodes)
#define BSZ 128
#define BSHS 10      // src bucket shift (1024 nodes)
#define BSZS 1024
#define SEGCAP 6144  // LDS staging for k_csr (mean 4096)

typedef float f32x2 __attribute__((ext_vector_type(2)));
typedef float f32x4 __attribute__((ext_vector_type(4)));
typedef __bf16 bf16x8 __attribute__((ext_vector_type(8)));

// ---- fp8 e4m3 (OCP, gfx950 HW cvt) ----
__device__ __forceinline__ unsigned char f32_to_fp8(float v) {
  unsigned r = __builtin_amdgcn_cvt_pk_fp8_f32(v, v, 0, false);
  return (unsigned char)(r & 0xFFu);
}

// ---- f32 -> bf16 RTNE (bit-manip) ----
__device__ __forceinline__ __bf16 f32_bf16(float f) {
  unsigned u = __float_as_uint(f);
  unsigned r = (u + 0x7FFFu + ((u >> 16) & 1u)) >> 16;
  return __builtin_bit_cast(__bf16, (unsigned short)r);
}

// ---- non-temporal load helper (streaming, avoid L2 pollution) ----
__device__ __forceinline__ int2 nt_i2(const int2* p) {
  long long v = __builtin_nontemporal_load((const long long*)p);
  return make_int2((int)(v & 0xFFFFFFFFll), (int)(v >> 32));
}

// ------- P1: per-(bucket, wg) counts, dst-buckets (128) and src-buckets (1024) -------
__global__ void k_count(const int* __restrict__ src, const int* __restrict__ dst,
                        int* __restrict__ cntAll, int NBD, int NBS, int E) {
  extern __shared__ int sh[];
  int* hD = sh;          // NBD
  int* hS = sh + NBD;    // NBS
  int tid = threadIdx.x, w = blockIdx.x;
  for (int k = tid; k < NBD + NBS; k += PT) sh[k] = 0;
  __syncthreads();
  int C = (E + NWG - 1) / NWG;
  int e0 = w * C, e1 = min(E, e0 + C);
  for (int e = e0 + tid; e < e1; e += PT) {
    atomicAdd(&hD[dst[e] >> BSH], 1);
    atomicAdd(&hS[src[e] >> BSHS], 1);
  }
  __syncthreads();
  for (int b = tid; b < NBD; b += PT) cntAll[b * NWG + w] = hD[b];
  for (int b = tid; b < NBS; b += PT) cntAll[(NBD + b) * NWG + w] = hS[b];
}

// ---------------- flat exclusive scan (in place), 1024-thread blocks ----------------
__global__ void k_scanA(int* __restrict__ data, int* __restrict__ partials, int TOT) {
  __shared__ int lds[1024];
  int tid = threadIdx.x;
  int g = blockIdx.x * 1024 + tid;
  int v = (g < TOT) ? data[g] : 0;
  lds[tid] = v; __syncthreads();
  for (int o = 1; o < 1024; o <<= 1) {
    int t = (tid >= o) ? lds[tid - o] : 0;
    __syncthreads();
    lds[tid] += t;
    __syncthreads();
  }
  if (g < TOT) data[g] = lds[tid] - v;
  if (tid == 1023) partials[blockIdx.x] = lds[1023];
}

__global__ void k_scanB(int* partials, int nb, unsigned* maxbits) {
  __shared__ int lds[1024];
  int tid = threadIdx.x;
  if (tid == 0) *maxbits = 0u;
  int v = (tid < nb) ? partials[tid] : 0;
  lds[tid] = v; __syncthreads();
  for (int o = 1; o < 1024; o <<= 1) {
    int t = (tid >= o) ? lds[tid - o] : 0;
    __syncthreads();
    lds[tid] += t;
    __syncthreads();
  }
  if (tid < nb) partials[tid] = lds[tid] - v;
}

__global__ void k_scanC(int* __restrict__ data, const int* __restrict__ partials, int TOT) {
  int g = blockIdx.x * 1024 + threadIdx.x;
  if (g < TOT) data[g] += partials[g >> 10];
}

// ------- P3: partition edges into dst-buckets (int2) and src-buckets (packed u32) -------
__global__ void k_part(const int* __restrict__ src, const int* __restrict__ dst,
                       const float* __restrict__ ew, const int* __restrict__ baseAll,
                       int2* __restrict__ gD, unsigned* __restrict__ gS,
                       int NBD, int NBS, int E) {
  extern __shared__ int sh[];
  int* cD = sh;
  int* cS = sh + NBD;
  int tid = threadIdx.x, w = blockIdx.x;
  for (int b = tid; b < NBD; b += PT) cD[b] = baseAll[b * NWG + w];
  for (int b = tid; b < NBS; b += PT) cS[b] = baseAll[(NBD + b) * NWG + w] - E;
  __syncthreads();
  int C = (E + NWG - 1) / NWG;
  int e0 = w * C, e1 = min(E, e0 + C);
  for (int e = e0 + tid; e < e1; e += PT) {
    int s = src[e], d = dst[e];
    float wv = ew[e];
    int pD = atomicAdd(&cD[d >> BSH], 1);
    gD[pD] = make_int2(s | ((d & (BSZ - 1)) << 24), __float_as_int(wv));
    int pS = atomicAdd(&cS[s >> BSHS], 1);
    gS[pS] = ((unsigned)(s & (BSZS - 1)) << 16) | (unsigned)__half_as_ushort(__float2half(wv));
  }
}

// ------- P4a: per-dst-bucket local counting sort -> CSR (in place) + off + dinv -------
__global__ void k_csr(int2* __restrict__ gD, const int* __restrict__ baseAll,
                      int* __restrict__ off, float* __restrict__ dinv,
                      int NBD, int N, int E) {
  __shared__ int2 seg[SEGCAP];
  __shared__ int hist[BSZ];
  __shared__ int curs[BSZ];
  __shared__ float degf[BSZ];
  int tid = threadIdx.x, b = blockIdx.x;
  int bstart = baseAll[b * NWG];
  int bend = (b + 1 < NBD) ? baseAll[(b + 1) * NWG] : E;
  int cnt = bend - bstart;
  for (int k = tid; k < cnt; k += 256) seg[k] = gD[bstart + k];
  if (tid < BSZ) { hist[tid] = 0; degf[tid] = 0.f; }
  __syncthreads();
  for (int k = tid; k < cnt; k += 256) {
    int dl = (unsigned)seg[k].x >> 24;
    atomicAdd(&hist[dl], 1);
    atomicAdd(&degf[dl], __int_as_float(seg[k].y));
  }
  __syncthreads();
  int v = (tid < BSZ) ? hist[tid] : 0;
  for (int o = 1; o < BSZ; o <<= 1) {
    int t = (tid < BSZ && tid >= o) ? hist[tid - o] : 0;
    __syncthreads();
    if (tid < BSZ) hist[tid] += t;
    __syncthreads();
  }
  if (tid < BSZ) {
    int excl = hist[tid] - v;
    curs[tid] = excl;
    int node = b * BSZ + tid;
    if (node < N) {
      off[node] = bstart + excl;
      dinv[node] = rsqrtf(1.0f + degf[tid]);
    }
  }
  if (b == NBD - 1 && tid == 0) off[N] = E;
  __syncthreads();
  for (int k = tid; k < cnt; k += 256) {
    int2 ev = seg[k];
    int dl = (unsigned)ev.x >> 24;
    int slot = atomicAdd(&curs[dl], 1);
    gD[bstart + slot] = make_int2(ev.x & 0xFFFFFF, ev.y);
  }
}

// ------- P4b: per-src-coarse-bucket weighted out-degree (dw) + global max -------
__global__ void k_dw(const unsigned* __restrict__ gS, const int* __restrict__ baseAll,
                     float* __restrict__ dw, unsigned* maxbits,
                     int NBD, int NBS, int N, int E) {
  __shared__ float acc[BSZS];
  int tid = threadIdx.x, b = blockIdx.x;
  int bstart = baseAll[(NBD + b) * NWG] - E;
  int bend = (b + 1 < NBS) ? baseAll[(NBD + b + 1) * NWG] - E : E;
  acc[tid] = 0.f;
  __syncthreads();
  for (int k = bstart + tid; k < bend; k += BSZS) {
    unsigned p = gS[k];
    atomicAdd(&acc[p >> 16], __half2float(__ushort_as_half((unsigned short)(p & 0xFFFFu))));
  }
  __syncthreads();
  float m = 0.f;
  int node = b * BSZS + tid;
  if (node < N) { dw[node] = acc[tid]; m = acc[tid]; }
  for (int mm = 32; mm; mm >>= 1) m = fmaxf(m, __shfl_xor(m, mm, 64));
  if ((tid & 63) == 0) atomicMax(maxbits, __float_as_uint(m));
}

// ------- g0 = dinv[i]*(x@W1), MFMA, stored fp8 in TWO halves g0a/g0b (N x 32 each) -------
// A: row=l&15, k=(l>>4)*8+i ; B: col=l&15, k=(l>>4)*8+i ; D: col=l&15, row=(l>>4)*4+reg
__global__ void k_gemm1(const float* __restrict__ x, const float* __restrict__ W1,
                        const float* __restrict__ dinv,
                        unsigned char* __restrict__ g0a, unsigned char* __restrict__ g0b, int N) {
  int lane = threadIdx.x & 63;
  int wid = (blockIdx.x * blockDim.x + threadIdx.x) >> 6;
  int nw = (gridDim.x * blockDim.x) >> 6;
  int l16 = lane & 15, lh = lane >> 4;
  bf16x8 bfrag[4][4];
#pragma unroll
  for (int cb = 0; cb < 4; ++cb)
#pragma unroll
    for (int kf = 0; kf < 4; ++kf)
#pragma unroll
      for (int i = 0; i < 8; ++i) {
        int k = kf * 32 + lh * 8 + i;
        bfrag[cb][kf][i] = f32_bf16(W1[k * F_HID + cb * 16 + l16]);
      }
  int ntiles = (N + 15) >> 4;
  for (int t = wid; t < ntiles; t += nw) {
    int rowbase = t << 4;
    int row = min(rowbase + l16, N - 1);
    bf16x8 afrag[4];
#pragma unroll
    for (int kf = 0; kf < 4; ++kf) {
      const f32x4* xp = (const f32x4*)(x + (size_t)row * F_IN + kf * 32 + lh * 8);
      f32x4 v0 = xp[0], v1 = xp[1];
#pragma unroll
      for (int i = 0; i < 4; ++i) afrag[kf][i] = f32_bf16(v0[i]);
#pragma unroll
      for (int i = 0; i < 4; ++i) afrag[kf][4 + i] = f32_bf16(v1[i]);
    }
    f32x4 acc[4] = {{0.f,0.f,0.f,0.f},{0.f,0.f,0.f,0.f},{0.f,0.f,0.f,0.f},{0.f,0.f,0.f,0.f}};
#pragma unroll
    for (int cb = 0; cb < 4; ++cb)
#pragma unroll
      for (int kf = 0; kf < 4; ++kf)
        acc[cb] = __builtin_amdgcn_mfma_f32_16x16x32_bf16(afrag[kf], bfrag[cb][kf], acc[cb], 0, 0, 0);
#pragma unroll
    for (int cb = 0; cb < 4; ++cb) {
      unsigned char* dstp = (cb < 2) ? g0a : g0b;
      int fl = (cb & 1) * 16 + l16;
#pragma unroll
      for (int r = 0; r < 4; ++r) {
        int rr = rowbase + lh * 4 + r;
        if (rr < N)
          dstp[(size_t)rr * 32 + fl] = f32_to_fp8(acc[cb][r] * dinv[rr]);
      }
    }
  }
}

// ------- layer-1 agg half-pass: wave/node; 16 edge-slots x 4 lanes x 8 features -------
// g0h = one 3.2MB half (L2-resident). finalPass: complete u[i]=di*(upart+pdt).
__global__ void k_agg1h(const unsigned char* __restrict__ g0h, const float* __restrict__ dinv,
                        const int* __restrict__ off, const int2* __restrict__ csr,
                        const float* __restrict__ b1h, const float* __restrict__ W2h,
                        float* __restrict__ upart, float* __restrict__ u,
                        int finalPass, int N) {
  int lane = threadIdx.x & 63;
  int grp = lane >> 2;        // edge slot 0..15
  int l4  = lane & 3;         // feature octet 0..3 (features 8*l4 .. 8*l4+7 of this half)
  int i = (blockIdx.x * blockDim.x + threadIdx.x) >> 6;
  if (i >= N) return;
  const uint2* g0v = (const uint2*)g0h;
  float acc[8] = {0.f, 0.f, 0.f, 0.f, 0.f, 0.f, 0.f, 0.f};
  if (grp == 0) {             // self contribution (g0 already dinv-scaled)
    uint2 rv = g0v[(size_t)i * 4 + l4];
    f32x2 c0 = __builtin_amdgcn_cvt_pk_f32_fp8(rv.x, false);
    f32x2 c1 = __builtin_amdgcn_cvt_pk_f32_fp8(rv.x, true);
    f32x2 c2 = __builtin_amdgcn_cvt_pk_f32_fp8(rv.y, false);
    f32x2 c3 = __builtin_amdgcn_cvt_pk_f32_fp8(rv.y, true);
    acc[0] += c0.x; acc[1] += c0.y; acc[2] += c1.x; acc[3] += c1.y;
    acc[4] += c2.x; acc[5] += c2.y; acc[6] += c3.x; acc[7] += c3.y;
  }
  int p0 = off[i], p1 = off[i + 1];
  for (int p = p0; p < p1; p += 64) {
    int m = min(p1 - p, 64);
    int2 ed = make_int2(0, 0);
    if (lane < m) ed = nt_i2(&csr[p + lane]);
#pragma unroll
    for (int jj = 0; jj < 4; ++jj) {
      int j = jj * 16 + grp;
      int s = __shfl(ed.x, j, 64);
      float w = __int_as_float(__shfl(ed.y, j, 64));
      if (j < m) {
        uint2 rv = g0v[(size_t)s * 4 + l4];
        f32x2 c0 = __builtin_amdgcn_cvt_pk_f32_fp8(rv.x, false);
        f32x2 c1 = __builtin_amdgcn_cvt_pk_f32_fp8(rv.x, true);
        f32x2 c2 = __builtin_amdgcn_cvt_pk_f32_fp8(rv.y, false);
        f32x2 c3 = __builtin_amdgcn_cvt_pk_f32_fp8(rv.y, true);
        acc[0] = fmaf(w, c0.x, acc[0]); acc[1] = fmaf(w, c0.y, acc[1]);
        acc[2] = fmaf(w, c1.x, acc[2]); acc[3] = fmaf(w, c1.y, acc[3]);
        acc[4] = fmaf(w, c2.x, acc[4]); acc[5] = fmaf(w, c2.y, acc[5]);
        acc[6] = fmaf(w, c3.x, acc[6]); acc[7] = fmaf(w, c3.y, acc[7]);
      }
    }
  }
  // fold 16 edge slots (lane bits 2..5)
#pragma unroll
  for (int k = 0; k < 8; ++k) {
    acc[k] += __shfl_xor(acc[k], 4, 64);
    acc[k] += __shfl_xor(acc[k], 8, 64);
    acc[k] += __shfl_xor(acc[k], 16, 64);
    acc[k] += __shfl_xor(acc[k], 32, 64);
  }
  float di = dinv[i];
  float pdt = 0.f;
#pragma unroll
  for (int k = 0; k < 8; ++k) {
    int f = l4 * 8 + k;
    float h = fmaxf(di * acc[k] + b1h[f], 0.f);
    pdt = fmaf(h, W2h[f], pdt);
  }
  pdt += __shfl_xor(pdt, 1, 64);
  pdt += __shfl_xor(pdt, 2, 64);
  if (lane == 0) {
    if (finalPass) u[i] = di * (upart[i] + pdt);
    else upart[i] = pdt;
  }
}

// ------- layer-2 agg + final: 2 nodes per wave (32-lane groups) -------
__global__ void k_agg2_final(const float* __restrict__ u, const float* __restrict__ dinv,
                             const int* __restrict__ off, const int2* __restrict__ csr,
                             const float* __restrict__ b2, const float* __restrict__ dw,
                             const unsigned* __restrict__ maxbits,
                             float* __restrict__ out, int N) {
  int lane32 = threadIdx.x & 31;
  int i = blockIdx.x * 8 + (threadIdx.x >> 5);
  if (i >= N) return;
  float acc = (lane32 == 0) ? u[i] : 0.f;
  int p0 = off[i], p1 = off[i + 1];
  for (int p = p0 + lane32; p < p1; p += 32) {
    int2 ed = csr[p];
    acc = fmaf(__int_as_float(ed.y), u[ed.x & 0xFFFFFF], acc);
  }
  for (int mm = 16; mm; mm >>= 1) acc += __shfl_xor(acc, mm, 64);
  if (lane32 == 0) {
    float md = __uint_as_float(*maxbits);
    float z = dinv[i] * acc + b2[0];
    float sc = 1.0f / (1.0f + expf(-z));
    out[i] = sc * (1.0f + dw[i] / md);
  }
}

extern "C" void kernel_launch(void* const* d_in, const int* in_sizes, int n_in,
                              void* d_out, int out_size, void* d_ws, size_t ws_size,
                              hipStream_t stream) {
  const float* x  = (const float*)d_in[0];
  const int*   ei = (const int*)d_in[1];
  const float* ew = (const float*)d_in[2];
  const float* W1 = (const float*)d_in[3];
  const float* b1 = (const float*)d_in[4];
  const float* W2 = (const float*)d_in[5];
  const float* b2 = (const float*)d_in[6];
  float* out = (float*)d_out;

  int N = out_size;      // 100000
  int E = in_sizes[2];   // 3200000
  const int* src = ei;
  const int* dst = ei + E;

  int NBD = (N + BSZ - 1) >> BSH;       // 782
  int NBS = (N + BSZS - 1) >> BSHS;     // 98
  int TOT = (NBD + NBS) * NWG;          // 225280
  int SB = (TOT + 1023) >> 10;          // 220
  size_t shmem = (size_t)(NBD + NBS) * sizeof(int);

  char* w8 = (char*)d_ws;
  int2*     gD      = (int2*)w8;                         // E int2 (becomes CSR in place)
  unsigned* gS      = (unsigned*)(gD + E);               // E u32
  int*      cntAll  = (int*)(gS + E);                    // TOT i (scanned in place)
  int*      partials= cntAll + TOT;                      // 1024 i
  int*      off     = partials + 1024;                   // N+1 i
  float*    dinv    = (float*)(off + N + 1);             // N f
  float*    dw      = dinv + N;                          // N f
  float*    u       = dw + N;                            // N f
  float*    upart   = u + N;                             // N f
  unsigned* maxbits = (unsigned*)(upart + N);            // 1 u
  unsigned char* g0a = (unsigned char*)(maxbits + 4);    // N*32 fp8 (half A)
  unsigned char* g0b = g0a + (size_t)N * 32;             // N*32 fp8 (half B)

  k_count<<<NWG, PT, shmem, stream>>>(src, dst, cntAll, NBD, NBS, E);
  k_scanA<<<SB, 1024, 0, stream>>>(cntAll, partials, TOT);
  k_scanB<<<1, 1024, 0, stream>>>(partials, SB, maxbits);
  k_scanC<<<SB, 1024, 0, stream>>>(cntAll, partials, TOT);
  k_part<<<NWG, PT, shmem, stream>>>(src, dst, ew, cntAll, gD, gS, NBD, NBS, E);
  k_csr<<<NBD, 256, 0, stream>>>(gD, cntAll, off, dinv, NBD, N, E);
  k_dw<<<NBS, BSZS, 0, stream>>>(gS, cntAll, dw, maxbits, NBD, NBS, N, E);
  k_gemm1<<<256, 256, 0, stream>>>(x, W1, dinv, g0a, g0b, N);
  k_agg1h<<<(N * 64 + 255) / 256, 256, 0, stream>>>(g0a, dinv, off, gD, b1, W2, upart, u, 0, N);
  k_agg1h<<<(N * 64 + 255) / 256, 256, 0, stream>>>(g0b, dinv, off, gD, b1 + 32, W2 + 32, upart, u, 1, N);
  k_agg2_final<<<(N + 7) / 8, 256, 0, stream>>>(u, dinv, off, gD, b2, dw, maxbits, out, N);
}

// Round 15
// 298.971 us; speedup vs baseline: 1.1158x; 1.1158x over previous
//
#include <hip/hip_runtime.h>
#include <hip/hip_fp16.h>
#include <math.h>

#define F_IN 128
#define F_HID 64
#define NWG 128      // partition chunks (halved: longer runs, less write-amp)
#define PT 1024      // threads per partition block
#define BSH 7        // dst bucket shift (128 nodes per bucket)
#define BSZ 128
#define BSHS 10      // src bucket shift (1024 nodes per bucket)
#define BSZS 1024
#define SEGCAP 6144  // max edges per dst-bucket staged in LDS (mean 4096)

typedef float f32x2 __attribute__((ext_vector_type(2)));
typedef float f32x4 __attribute__((ext_vector_type(4)));
typedef __bf16 bf16x8 __attribute__((ext_vector_type(8)));

// ---- fp8 e4m3 (OCP, gfx950 HW cvt) ----
__device__ __forceinline__ unsigned char f32_to_fp8(float v) {
  unsigned r = __builtin_amdgcn_cvt_pk_fp8_f32(v, v, 0, false);
  return (unsigned char)(r & 0xFFu);
}

// ---- f32 -> bf16 RTNE (bit-manip) ----
__device__ __forceinline__ __bf16 f32_bf16(float f) {
  unsigned u = __float_as_uint(f);
  unsigned r = (u + 0x7FFFu + ((u >> 16) & 1u)) >> 16;
  return __builtin_bit_cast(__bf16, (unsigned short)r);
}

// ---- non-temporal load (stream past L2; used for the once-read CSR in agg1) ----
__device__ __forceinline__ int2 nt_i2(const int2* p) {
  long long v = __builtin_nontemporal_load((const long long*)p);
  return make_int2((int)(v & 0xFFFFFFFFll), (int)(v >> 32));
}

// ------- P1: per-(bucket, wg) counts, dst-buckets (128) and src-buckets (1024) -------
__global__ void k_count(const int* __restrict__ src, const int* __restrict__ dst,
                        int* __restrict__ cntAll, int NBD, int NBS, int E) {
  extern __shared__ int sh[];
  int* hD = sh;          // NBD
  int* hS = sh + NBD;    // NBS
  int tid = threadIdx.x, w = blockIdx.x;
  for (int k = tid; k < NBD + NBS; k += PT) sh[k] = 0;
  __syncthreads();
  int C = (E + NWG - 1) / NWG;
  int e0 = w * C, e1 = min(E, e0 + C);
  for (int e = e0 + tid; e < e1; e += PT) {
    atomicAdd(&hD[dst[e] >> BSH], 1);
    atomicAdd(&hS[src[e] >> BSHS], 1);
  }
  __syncthreads();
  for (int b = tid; b < NBD; b += PT) cntAll[b * NWG + w] = hD[b];
  for (int b = tid; b < NBS; b += PT) cntAll[(NBD + b) * NWG + w] = hS[b];
}

// ---------------- flat exclusive scan (in place), 1024-thread blocks ----------------
__global__ void k_scanA(int* __restrict__ data, int* __restrict__ partials, int TOT) {
  __shared__ int lds[1024];
  int tid = threadIdx.x;
  int g = blockIdx.x * 1024 + tid;
  int v = (g < TOT) ? data[g] : 0;
  lds[tid] = v; __syncthreads();
  for (int o = 1; o < 1024; o <<= 1) {
    int t = (tid >= o) ? lds[tid - o] : 0;
    __syncthreads();
    lds[tid] += t;
    __syncthreads();
  }
  if (g < TOT) data[g] = lds[tid] - v;
  if (tid == 1023) partials[blockIdx.x] = lds[1023];
}

__global__ void k_scanB(int* partials, int nb, unsigned* maxbits) {
  __shared__ int lds[1024];
  int tid = threadIdx.x;
  if (tid == 0) *maxbits = 0u;
  int v = (tid < nb) ? partials[tid] : 0;
  lds[tid] = v; __syncthreads();
  for (int o = 1; o < 1024; o <<= 1) {
    int t = (tid >= o) ? lds[tid - o] : 0;
    __syncthreads();
    lds[tid] += t;
    __syncthreads();
  }
  if (tid < nb) partials[tid] = lds[tid] - v;
}

__global__ void k_scanC(int* __restrict__ data, const int* __restrict__ partials, int TOT) {
  int g = blockIdx.x * 1024 + threadIdx.x;
  if (g < TOT) data[g] += partials[g >> 10];
}

// ------- P3: partition edges into dst-buckets (int2) and src-buckets (packed u32) -------
__global__ void k_part(const int* __restrict__ src, const int* __restrict__ dst,
                       const float* __restrict__ ew, const int* __restrict__ baseAll,
                       int2* __restrict__ gD, unsigned* __restrict__ gS,
                       int NBD, int NBS, int E) {
  extern __shared__ int sh[];
  int* cD = sh;
  int* cS = sh + NBD;
  int tid = threadIdx.x, w = blockIdx.x;
  for (int b = tid; b < NBD; b += PT) cD[b] = baseAll[b * NWG + w];
  for (int b = tid; b < NBS; b += PT) cS[b] = baseAll[(NBD + b) * NWG + w] - E;
  __syncthreads();
  int C = (E + NWG - 1) / NWG;
  int e0 = w * C, e1 = min(E, e0 + C);
  for (int e = e0 + tid; e < e1; e += PT) {
    int s = src[e], d = dst[e];
    float wv = ew[e];
    int pD = atomicAdd(&cD[d >> BSH], 1);
    gD[pD] = make_int2(s | ((d & (BSZ - 1)) << 24), __float_as_int(wv));
    int pS = atomicAdd(&cS[s >> BSHS], 1);
    gS[pS] = ((unsigned)(s & (BSZS - 1)) << 16) | (unsigned)__half_as_ushort(__float2half(wv));
  }
}

// ------- P4a: per-dst-bucket local counting sort -> CSR (in place) + off + dinv -------
__global__ void k_csr(int2* __restrict__ gD, const int* __restrict__ baseAll,
                      int* __restrict__ off, float* __restrict__ dinv,
                      int NBD, int N, int E) {
  __shared__ int2 seg[SEGCAP];
  __shared__ int hist[BSZ];
  __shared__ int curs[BSZ];
  __shared__ float degf[BSZ];
  int tid = threadIdx.x, b = blockIdx.x;
  int bstart = baseAll[b * NWG];
  int bend = (b + 1 < NBD) ? baseAll[(b + 1) * NWG] : E;
  int cnt = bend - bstart;
  for (int k = tid; k < cnt; k += 256) seg[k] = gD[bstart + k];
  if (tid < BSZ) { hist[tid] = 0; degf[tid] = 0.f; }
  __syncthreads();
  for (int k = tid; k < cnt; k += 256) {
    int dl = (unsigned)seg[k].x >> 24;
    atomicAdd(&hist[dl], 1);
    atomicAdd(&degf[dl], __int_as_float(seg[k].y));
  }
  __syncthreads();
  int v = (tid < BSZ) ? hist[tid] : 0;
  for (int o = 1; o < BSZ; o <<= 1) {
    int t = (tid < BSZ && tid >= o) ? hist[tid - o] : 0;
    __syncthreads();
    if (tid < BSZ) hist[tid] += t;
    __syncthreads();
  }
  if (tid < BSZ) {
    int excl = hist[tid] - v;
    curs[tid] = excl;
    int node = b * BSZ + tid;
    if (node < N) {
      off[node] = bstart + excl;
      dinv[node] = rsqrtf(1.0f + degf[tid]);
    }
  }
  if (b == NBD - 1 && tid == 0) off[N] = E;
  __syncthreads();
  for (int k = tid; k < cnt; k += 256) {
    int2 ev = seg[k];
    int dl = (unsigned)ev.x >> 24;
    int slot = atomicAdd(&curs[dl], 1);
    gD[bstart + slot] = make_int2(ev.x & 0xFFFFFF, ev.y);
  }
}

// ------- P4b: per-src-coarse-bucket weighted out-degree (dw) + global max -------
__global__ void k_dw(const unsigned* __restrict__ gS, const int* __restrict__ baseAll,
                     float* __restrict__ dw, unsigned* maxbits,
                     int NBD, int NBS, int N, int E) {
  __shared__ float acc[BSZS];
  int tid = threadIdx.x, b = blockIdx.x;
  int bstart = baseAll[(NBD + b) * NWG] - E;
  int bend = (b + 1 < NBS) ? baseAll[(NBD + b + 1) * NWG] - E : E;
  acc[tid] = 0.f;
  __syncthreads();
  for (int k = bstart + tid; k < bend; k += BSZS) {
    unsigned p = gS[k];
    atomicAdd(&acc[p >> 16], __half2float(__ushort_as_half((unsigned short)(p & 0xFFFFu))));
  }
  __syncthreads();
  float m = 0.f;
  int node = b * BSZS + tid;
  if (node < N) { dw[node] = acc[tid]; m = acc[tid]; }
  for (int mm = 32; mm; mm >>= 1) m = fmaxf(m, __shfl_xor(m, mm, 64));
  if ((tid & 63) == 0) atomicMax(maxbits, __float_as_uint(m));
}

// ------- g0 = dinv[i] * (x @ W1) row, MFMA 16x16x32 bf16, stored fp8 e4m3 -------
// A: row=l&15, k=(l>>4)*8+i ; B: col=l&15, k=(l>>4)*8+i ; D: col=l&15, row=(l>>4)*4+reg
__global__ void k_gemm1(const float* __restrict__ x, const float* __restrict__ W1,
                        const float* __restrict__ dinv, unsigned char* __restrict__ g0, int N) {
  int lane = threadIdx.x & 63;
  int wid = (blockIdx.x * blockDim.x + threadIdx.x) >> 6;
  int nw = (gridDim.x * blockDim.x) >> 6;
  int l16 = lane & 15, lh = lane >> 4;
  bf16x8 bfrag[4][4];
#pragma unroll
  for (int cb = 0; cb < 4; ++cb)
#pragma unroll
    for (int kf = 0; kf < 4; ++kf)
#pragma unroll
      for (int i = 0; i < 8; ++i) {
        int k = kf * 32 + lh * 8 + i;
        bfrag[cb][kf][i] = f32_bf16(W1[k * F_HID + cb * 16 + l16]);
      }
  int ntiles = (N + 15) >> 4;
  for (int t = wid; t < ntiles; t += nw) {
    int rowbase = t << 4;
    int row = min(rowbase + l16, N - 1);
    bf16x8 afrag[4];
#pragma unroll
    for (int kf = 0; kf < 4; ++kf) {
      const f32x4* xp = (const f32x4*)(x + (size_t)row * F_IN + kf * 32 + lh * 8);
      f32x4 v0 = xp[0], v1 = xp[1];
#pragma unroll
      for (int i = 0; i < 4; ++i) afrag[kf][i] = f32_bf16(v0[i]);
#pragma unroll
      for (int i = 0; i < 4; ++i) afrag[kf][4 + i] = f32_bf16(v1[i]);
    }
    f32x4 acc[4] = {{0.f,0.f,0.f,0.f},{0.f,0.f,0.f,0.f},{0.f,0.f,0.f,0.f},{0.f,0.f,0.f,0.f}};
#pragma unroll
    for (int cb = 0; cb < 4; ++cb)
#pragma unroll
      for (int kf = 0; kf < 4; ++kf)
        acc[cb] = __builtin_amdgcn_mfma_f32_16x16x32_bf16(afrag[kf], bfrag[cb][kf], acc[cb], 0, 0, 0);
    if (rowbase + 16 <= N) {
      f32x4 dv = *(const f32x4*)(dinv + rowbase + lh * 4);
#pragma unroll
      for (int cb = 0; cb < 4; ++cb)
#pragma unroll
        for (int r = 0; r < 4; ++r) {
          int rr = rowbase + lh * 4 + r;
          g0[(size_t)rr * F_HID + cb * 16 + l16] = f32_to_fp8(acc[cb][r] * dv[r]);
        }
    } else {
#pragma unroll
      for (int cb = 0; cb < 4; ++cb)
#pragma unroll
        for (int r = 0; r < 4; ++r) {
          int rr = rowbase + lh * 4 + r;
          if (rr < N)
            g0[(size_t)rr * F_HID + cb * 16 + l16] = f32_to_fp8(acc[cb][r] * dinv[rr]);
        }
    }
  }
}

// ------- layer-1 agg: wave per node; 8 edge-slots x 8 lanes x 8 features -------
__global__ void k_agg1(const unsigned char* __restrict__ g0, const float* __restrict__ dinv,
                       const int* __restrict__ off, const int2* __restrict__ csr,
                       const float* __restrict__ b1, const float* __restrict__ W2,
                       float* __restrict__ u, int N) {
  int lane = threadIdx.x & 63;
  int grp = lane >> 3;        // edge slot 0..7
  int l8  = lane & 7;         // feature octet 0..7
  int i = (blockIdx.x * blockDim.x + threadIdx.x) >> 6;
  if (i >= N) return;
  const uint2* g0v = (const uint2*)g0;
  float acc[8] = {0.f, 0.f, 0.f, 0.f, 0.f, 0.f, 0.f, 0.f};
  if (grp == 0) {             // self contribution once (group 0)
    uint2 rv = g0v[(size_t)i * 8 + l8];
    f32x2 c0 = __builtin_amdgcn_cvt_pk_f32_fp8(rv.x, false);
    f32x2 c1 = __builtin_amdgcn_cvt_pk_f32_fp8(rv.x, true);
    f32x2 c2 = __builtin_amdgcn_cvt_pk_f32_fp8(rv.y, false);
    f32x2 c3 = __builtin_amdgcn_cvt_pk_f32_fp8(rv.y, true);
    acc[0] += c0.x; acc[1] += c0.y; acc[2] += c1.x; acc[3] += c1.y;
    acc[4] += c2.x; acc[5] += c2.y; acc[6] += c3.x; acc[7] += c3.y;
  }
  int p0 = off[i], p1 = off[i + 1];
  for (int p = p0; p < p1; p += 64) {
    int m = min(p1 - p, 64);
    int2 ed = make_int2(0, 0);
    if (lane < m) ed = nt_i2(&csr[p + lane]);   // stream CSR past L2
#pragma unroll
    for (int jj = 0; jj < 8; ++jj) {
      int j = jj * 8 + grp;
      int s = __shfl(ed.x, j, 64);
      float w = __int_as_float(__shfl(ed.y, j, 64));
      if (j < m) {
        uint2 rv = g0v[(size_t)s * 8 + l8];
        f32x2 c0 = __builtin_amdgcn_cvt_pk_f32_fp8(rv.x, false);
        f32x2 c1 = __builtin_amdgcn_cvt_pk_f32_fp8(rv.x, true);
        f32x2 c2 = __builtin_amdgcn_cvt_pk_f32_fp8(rv.y, false);
        f32x2 c3 = __builtin_amdgcn_cvt_pk_f32_fp8(rv.y, true);
        acc[0] = fmaf(w, c0.x, acc[0]); acc[1] = fmaf(w, c0.y, acc[1]);
        acc[2] = fmaf(w, c1.x, acc[2]); acc[3] = fmaf(w, c1.y, acc[3]);
        acc[4] = fmaf(w, c2.x, acc[4]); acc[5] = fmaf(w, c2.y, acc[5]);
        acc[6] = fmaf(w, c3.x, acc[6]); acc[7] = fmaf(w, c3.y, acc[7]);
      }
    }
  }
#pragma unroll
  for (int k = 0; k < 8; ++k) {
    acc[k] += __shfl_xor(acc[k], 8, 64);
    acc[k] += __shfl_xor(acc[k], 16, 64);
    acc[k] += __shfl_xor(acc[k], 32, 64);
  }
  float di = dinv[i];
  float pdt = 0.f;
#pragma unroll
  for (int k = 0; k < 8; ++k) {
    int f = l8 * 8 + k;
    float h = fmaxf(di * acc[k] + b1[f], 0.f);
    pdt = fmaf(h, W2[f], pdt);
  }
  pdt += __shfl_xor(pdt, 1, 64);
  pdt += __shfl_xor(pdt, 2, 64);
  pdt += __shfl_xor(pdt, 4, 64);
  if (lane == 0) u[i] = di * pdt;
}

// ------- layer-2 agg + final: 2 nodes per wave (32-lane groups) -------
__global__ void k_agg2_final(const float* __restrict__ u, const float* __restrict__ dinv,
                             const int* __restrict__ off, const int2* __restrict__ csr,
                             const float* __restrict__ b2, const float* __restrict__ dw,
                             const unsigned* __restrict__ maxbits,
                             float* __restrict__ out, int N) {
  int lane32 = threadIdx.x & 31;
  int i = blockIdx.x * 8 + (threadIdx.x >> 5);
  if (i >= N) return;
  float acc = (lane32 == 0) ? u[i] : 0.f;
  int p0 = off[i], p1 = off[i + 1];
  for (int p = p0 + lane32; p < p1; p += 32) {
    int2 ed = csr[p];
    acc = fmaf(__int_as_float(ed.y), u[ed.x], acc);
  }
  for (int mm = 16; mm; mm >>= 1) acc += __shfl_xor(acc, mm, 64);
  if (lane32 == 0) {
    float md = __uint_as_float(*maxbits);
    float z = dinv[i] * acc + b2[0];
    float sc = 1.0f / (1.0f + expf(-z));
    out[i] = sc * (1.0f + dw[i] / md);
  }
}

extern "C" void kernel_launch(void* const* d_in, const int* in_sizes, int n_in,
                              void* d_out, int out_size, void* d_ws, size_t ws_size,
                              hipStream_t stream) {
  const float* x  = (const float*)d_in[0];
  const int*   ei = (const int*)d_in[1];
  const float* ew = (const float*)d_in[2];
  const float* W1 = (const float*)d_in[3];
  const float* b1 = (const float*)d_in[4];
  const float* W2 = (const float*)d_in[5];
  const float* b2 = (const float*)d_in[6];
  float* out = (float*)d_out;

  int N = out_size;      // 100000
  int E = in_sizes[2];   // 3200000
  const int* src = ei;
  const int* dst = ei + E;

  int NBD = (N + BSZ - 1) >> BSH;       // 782
  int NBS = (N + BSZS - 1) >> BSHS;     // 98
  int TOT = (NBD + NBS) * NWG;          // 112640
  int SB = (TOT + 1023) >> 10;          // 110
  size_t shmem = (size_t)(NBD + NBS) * sizeof(int);

  char* w8 = (char*)d_ws;
  int2*     gD      = (int2*)w8;                         // E int2  (becomes CSR in place)
  unsigned* gS      = (unsigned*)(gD + E);               // E u32
  int*      cntAll  = (int*)(gS + E);                    // TOT i  (scanned in place)
  int*      partials= cntAll + TOT;                      // 1024 i
  int*      off     = partials + 1024;                   // N+1 i
  float*    dinv    = (float*)(off + N + 1);             // N f
  float*    dw      = dinv + N;                          // N f
  float*    u       = dw + N;                            // N f
  unsigned* maxbits = (unsigned*)(u + N);                // 1 u
  unsigned char* g0 = (unsigned char*)(maxbits + 4);     // N*64 fp8

  k_count<<<NWG, PT, shmem, stream>>>(src, dst, cntAll, NBD, NBS, E);
  k_scanA<<<SB, 1024, 0, stream>>>(cntAll, partials, TOT);
  k_scanB<<<1, 1024, 0, stream>>>(partials, SB, maxbits);
  k_scanC<<<SB, 1024, 0, stream>>>(cntAll, partials, TOT);
  k_part<<<NWG, PT, shmem, stream>>>(src, dst, ew, cntAll, gD, gS, NBD, NBS, E);
  k_csr<<<NBD, 256, 0, stream>>>(gD, cntAll, off, dinv, NBD, N, E);
  k_dw<<<NBS, BSZS, 0, stream>>>(gS, cntAll, dw, maxbits, NBD, NBS, N, E);
  k_gemm1<<<256, 256, 0, stream>>>(x, W1, dinv, g0, N);
  k_agg1<<<(N * 64 + 255) / 256, 256, 0, stream>>>(g0, dinv, off, gD, b1, W2, u, N);
  k_agg2_final<<<(N + 7) / 8, 256, 0, stream>>>(u, dinv, off, gD, b2, dw, maxbits, out, N);
}